// Round 10
// baseline (1505.147 us; speedup 1.0000x reference)
//
#include <hip/hip_runtime.h>

// R10: structural split. For t < T, LSTM1 never depends on LSTM2, and LSTM2
// only needs z[t] = W_ih2 . h1(t) (4 scalars). So:
//   Kernel A (2048 blocks x 1 wave): LSTM1-only recurrence + z-stream to ws.
//     - h1 broadcast via LDS row (1 ds_write + 26 same-address ds_read_b64
//       broadcasts, conflict-free) instead of 52 v_readlane + SGPR packing
//       (removes the VALU->SGPR hazard chains).
//     - z via the proven DPP tree; lane 63 stores float4 z[t] to ws.
//     - halves the transcendental count in the hot loop (LSTM2's 10 gone).
//   Kernel B (32 blocks x 64): scalar LSTM2 recurrence per sequence off the
//     z-stream; writes out[t<T] and final (h2,c2) state.
//   Kernel C (2048 blocks x 1 wave): R9's proven fused loop for the 64
//     future steps (x = h2 feedback), seeded from saved states.
//
// VGPR_Count granule discovery: rocprof reports granules of 2 (R5-R9's "124"
// = 248 regs = weights resident all along). Weights stay "+v" operands of the
// MAC asm (proven residency pattern).

#define H1N 51
#define NP  26   // k-pairs, covers k=0..51 (k=51 weight = 0)
#define WAVE 64
#define BATCH 2048

typedef float v2f __attribute__((ext_vector_type(2)));

#define INV_LN2   1.44269504088896340736f
#define INV_LN2X2 2.88539008177792681472f

__device__ __forceinline__ float sigmoid_s(float xs) {   // input pre-scaled by 1/ln2
    return __builtin_amdgcn_rcpf(1.0f + __builtin_amdgcn_exp2f(-xs));
}
__device__ __forceinline__ float tanh_s2(float xs2) {    // input pre-scaled by 2/ln2
    float e = __builtin_amdgcn_exp2f(xs2);
    return fmaf(-2.0f, __builtin_amdgcn_rcpf(e + 1.0f), 1.0f);
}
__device__ __forceinline__ float tanh_nat(float x) {
    return tanh_s2(x * INV_LN2X2);
}
__device__ __forceinline__ float rdlane(float v, int k) {
    return __int_as_float(__builtin_amdgcn_readlane(__float_as_int(v), k));
}

template<int CTRL, int RM, int BM>
__device__ __forceinline__ void dpp_stage4(float& a, float& b, float& c, float& d) {
    int ta = __builtin_amdgcn_update_dpp(0, __float_as_int(a), CTRL, RM, BM, false);
    int tb = __builtin_amdgcn_update_dpp(0, __float_as_int(b), CTRL, RM, BM, false);
    int tc = __builtin_amdgcn_update_dpp(0, __float_as_int(c), CTRL, RM, BM, false);
    int td = __builtin_amdgcn_update_dpp(0, __float_as_int(d), CTRL, RM, BM, false);
    a += __int_as_float(ta); b += __int_as_float(tb);
    c += __int_as_float(tc); d += __int_as_float(td);
}
__device__ __forceinline__ void wave_sum4(float& p0, float& p1, float& p2, float& p3) {
    dpp_stage4<0x111, 0xf, 0xf>(p0, p1, p2, p3);  // row_shr:1
    dpp_stage4<0x112, 0xf, 0xf>(p0, p1, p2, p3);  // row_shr:2
    dpp_stage4<0x114, 0xf, 0xe>(p0, p1, p2, p3);  // row_shr:4
    dpp_stage4<0x118, 0xf, 0xc>(p0, p1, p2, p3);  // row_shr:8
    dpp_stage4<0x142, 0xa, 0xf>(p0, p1, p2, p3);  // row_bcast:15
    dpp_stage4<0x143, 0xc, 0xf>(p0, p1, p2, p3);  // row_bcast:31  (total in lane 63)
}

// ---------------- Kernel A: LSTM1 warm phase + z-stream ----------------
__global__ __attribute__((amdgpu_flat_work_group_size(64, 64),
                          amdgpu_waves_per_eu(2, 2)))
void lstm1_pass(const float* __restrict__ input,   // [B, T]
                const float* __restrict__ W_ih1,   // [204, 1]
                const float* __restrict__ W_hh1,   // [204, 51]
                const float* __restrict__ b_ih1,   // [204]
                const float* __restrict__ b_hh1,   // [204]
                const float* __restrict__ W_ih2,   // [4, 51]
                float4* __restrict__ zws,          // [T, BATCH]
                float* __restrict__ h1s,           // [BATCH, 51]
                float* __restrict__ c1s,           // [BATCH, 51]
                int T)
{
    const int j   = threadIdx.x;
    const bool jv = (j < H1N);
    const int jj  = jv ? j : 0;
    const float m = jv ? 1.0f : 0.0f;
    const int b   = blockIdx.x;

    const int r_i = jj, r_f = H1N + jj, r_g = 2*H1N + jj, r_o = 3*H1N + jj;
    const float s_i = m * INV_LN2, s_f = m * INV_LN2;
    const float s_g = m * INV_LN2X2, s_o = m * INV_LN2;

    v2f wI[NP], wF[NP], wG[NP], wO[NP];
#pragma unroll
    for (int kk = 0; kk < NP; ++kk) {
        const int k0 = 2*kk, k1 = 2*kk + 1;
        const float n0 = (k0 < H1N) ? 1.0f : 0.0f;
        const float n1 = (k1 < H1N) ? 1.0f : 0.0f;
        const int c0 = (k0 < H1N) ? k0 : 0, c1i = (k1 < H1N) ? k1 : 0;
        wI[kk].x = s_i * n0 * W_hh1[r_i*H1N + c0];  wI[kk].y = s_i * n1 * W_hh1[r_i*H1N + c1i];
        wF[kk].x = s_f * n0 * W_hh1[r_f*H1N + c0];  wF[kk].y = s_f * n1 * W_hh1[r_f*H1N + c1i];
        wG[kk].x = s_g * n0 * W_hh1[r_g*H1N + c0];  wG[kk].y = s_g * n1 * W_hh1[r_g*H1N + c1i];
        wO[kk].x = s_o * n0 * W_hh1[r_o*H1N + c0];  wO[kk].y = s_o * n1 * W_hh1[r_o*H1N + c1i];
    }
    const float b_i = s_i * (b_ih1[r_i] + b_hh1[r_i]);
    const float b_f = s_f * (b_ih1[r_f] + b_hh1[r_f]);
    const float b_g = s_g * (b_ih1[r_g] + b_hh1[r_g]);
    const float b_o = s_o * (b_ih1[r_o] + b_hh1[r_o]);
    const float wx_i = s_i * W_ih1[r_i];
    const float wx_f = s_f * W_ih1[r_f];
    const float wx_g = s_g * W_ih1[r_g];
    const float wx_o = s_o * W_ih1[r_o];

    // LSTM2 input weights (pre-scaled per destination gate).
    float wi2_0 = m * INV_LN2   * W_ih2[0*H1N + jj];
    float wi2_1 = m * INV_LN2   * W_ih2[1*H1N + jj];
    float wi2_2 = m * INV_LN2X2 * W_ih2[2*H1N + jj];
    float wi2_3 = m * INV_LN2   * W_ih2[3*H1N + jj];

    __shared__ __align__(16) float hrow[64];
    hrow[j] = 0.0f;                         // h1(t=-1) = 0

    float h1 = 0.0f, c1 = 0.0f;
    const float* __restrict__ xrow = input + (long)b * T;
    float xbuf = 0.0f;

    for (int t = 0; t < T; ++t) {
        asm volatile("" : "+v"(wi2_0), "+v"(wi2_1), "+v"(wi2_2), "+v"(wi2_3));

        if ((t & 63) == 0) xbuf = xrow[t + j];     // coalesced, once per 64
        const float x = rdlane(xbuf, t & 63);

        // ---- LSTM1 matvec: h-pairs broadcast from LDS (ds_read_b64, all
        // lanes same address => broadcast); weights "+v" in the MAC asm ----
        v2f aI = {fmaf(wx_i, x, b_i), 0.0f};
        v2f aF = {fmaf(wx_f, x, b_f), 0.0f};
        v2f aG = {fmaf(wx_g, x, b_g), 0.0f};
        v2f aO = {fmaf(wx_o, x, b_o), 0.0f};
#pragma unroll
        for (int kk = 0; kk < NP; ++kk) {
            const v2f hp = *(const v2f*)&hrow[2*kk];
            asm("v_pk_fma_f32 %0, %4, %8, %0\n\t"
                "v_pk_fma_f32 %1, %5, %8, %1\n\t"
                "v_pk_fma_f32 %2, %6, %8, %2\n\t"
                "v_pk_fma_f32 %3, %7, %8, %3"
                : "+v"(aI), "+v"(aF), "+v"(aG), "+v"(aO),
                  "+v"(wI[kk]), "+v"(wF[kk]), "+v"(wG[kk]), "+v"(wO[kk])
                : "v"(hp));
        }
        const float gi = sigmoid_s(aI.x + aI.y);
        const float gf = sigmoid_s(aF.x + aF.y);
        const float gg = tanh_s2 (aG.x + aG.y);
        const float go = sigmoid_s(aO.x + aO.y);
        c1 = fmaf(gf, c1, gi * gg);
        h1 = go * tanh_nat(c1);

        hrow[j] = jv ? h1 : 0.0f;   // publish h1(t) for step t+1 (same wave)

        // ---- z[t] = W_ih2 . h1 (4 dots, DPP tree); lane 63 stores ----
        float p0 = wi2_0 * h1, p1 = wi2_1 * h1, p2 = wi2_2 * h1, p3 = wi2_3 * h1;
        wave_sum4(p0, p1, p2, p3);
        if (j == 63) zws[(long)t * BATCH + b] = make_float4(p0, p1, p2, p3);
    }

    if (jv) { h1s[b*H1N + j] = h1; c1s[b*H1N + j] = c1; }
}

// ---------------- Kernel B: scalar LSTM2 recurrence off the z-stream -------
__global__ void lstm2_pass(const float4* __restrict__ zws,   // [T, BATCH]
                           const float* __restrict__ W_hh2,  // [4,1]
                           const float* __restrict__ b_ih2,  // [4]
                           const float* __restrict__ b_hh2,  // [4]
                           float* __restrict__ out,          // [B, TF]
                           float2* __restrict__ h2c2,        // [BATCH]
                           int T, int TF)
{
    const int s = blockIdx.x * WAVE + threadIdx.x;   // sequence
    const float wh2_0 = INV_LN2*W_hh2[0], wh2_1 = INV_LN2*W_hh2[1];
    const float wh2_2 = INV_LN2X2*W_hh2[2], wh2_3 = INV_LN2*W_hh2[3];
    const float b2_0 = INV_LN2*(b_ih2[0] + b_hh2[0]), b2_1 = INV_LN2*(b_ih2[1] + b_hh2[1]);
    const float b2_2 = INV_LN2X2*(b_ih2[2] + b_hh2[2]), b2_3 = INV_LN2*(b_ih2[3] + b_hh2[3]);

    float h2 = 0.0f, c2 = 0.0f;
    float* __restrict__ orow = out + (long)s * TF;
    for (int t = 0; t < T; ++t) {
        const float4 z = zws[(long)t * BATCH + s];   // coalesced across lanes
        const float g2i = sigmoid_s(fmaf(wh2_0, h2, b2_0 + z.x));
        const float g2f = sigmoid_s(fmaf(wh2_1, h2, b2_1 + z.y));
        const float g2g = tanh_s2 (fmaf(wh2_2, h2, b2_2 + z.z));
        const float g2o = sigmoid_s(fmaf(wh2_3, h2, b2_3 + z.w));
        c2 = fmaf(g2f, c2, g2i * g2g);
        h2 = g2o * tanh_nat(c2);
        orow[t] = h2;
    }
    h2c2[s] = make_float2(h2, c2);
}

// ---------------- Kernel C: fused future phase (64 steps, x = h2) ----------
__global__ __attribute__((amdgpu_flat_work_group_size(64, 64),
                          amdgpu_waves_per_eu(2, 2)))
void lstm_future(const float* __restrict__ W_ih1, const float* __restrict__ W_hh1,
                 const float* __restrict__ b_ih1, const float* __restrict__ b_hh1,
                 const float* __restrict__ W_ih2, const float* __restrict__ W_hh2,
                 const float* __restrict__ b_ih2, const float* __restrict__ b_hh2,
                 const float* __restrict__ h1s, const float* __restrict__ c1s,
                 const float2* __restrict__ h2c2,
                 float* __restrict__ out, int T, int TF)
{
    const int j   = threadIdx.x;
    const bool jv = (j < H1N);
    const int jj  = jv ? j : 0;
    const float m = jv ? 1.0f : 0.0f;
    const int b   = blockIdx.x;

    const int r_i = jj, r_f = H1N + jj, r_g = 2*H1N + jj, r_o = 3*H1N + jj;
    const float s_i = m * INV_LN2, s_f = m * INV_LN2;
    const float s_g = m * INV_LN2X2, s_o = m * INV_LN2;

    v2f wI[NP], wF[NP], wG[NP], wO[NP];
#pragma unroll
    for (int kk = 0; kk < NP; ++kk) {
        const int k0 = 2*kk, k1 = 2*kk + 1;
        const float n0 = (k0 < H1N) ? 1.0f : 0.0f;
        const float n1 = (k1 < H1N) ? 1.0f : 0.0f;
        const int c0 = (k0 < H1N) ? k0 : 0, c1i = (k1 < H1N) ? k1 : 0;
        wI[kk].x = s_i * n0 * W_hh1[r_i*H1N + c0];  wI[kk].y = s_i * n1 * W_hh1[r_i*H1N + c1i];
        wF[kk].x = s_f * n0 * W_hh1[r_f*H1N + c0];  wF[kk].y = s_f * n1 * W_hh1[r_f*H1N + c1i];
        wG[kk].x = s_g * n0 * W_hh1[r_g*H1N + c0];  wG[kk].y = s_g * n1 * W_hh1[r_g*H1N + c1i];
        wO[kk].x = s_o * n0 * W_hh1[r_o*H1N + c0];  wO[kk].y = s_o * n1 * W_hh1[r_o*H1N + c1i];
    }
    const float b_i = s_i * (b_ih1[r_i] + b_hh1[r_i]);
    const float b_f = s_f * (b_ih1[r_f] + b_hh1[r_f]);
    const float b_g = s_g * (b_ih1[r_g] + b_hh1[r_g]);
    const float b_o = s_o * (b_ih1[r_o] + b_hh1[r_o]);
    const float wx_i = s_i * W_ih1[r_i];
    const float wx_f = s_f * W_ih1[r_f];
    const float wx_g = s_g * W_ih1[r_g];
    const float wx_o = s_o * W_ih1[r_o];

    float wi2_0 = m * INV_LN2   * W_ih2[0*H1N + jj];
    float wi2_1 = m * INV_LN2   * W_ih2[1*H1N + jj];
    float wi2_2 = m * INV_LN2X2 * W_ih2[2*H1N + jj];
    float wi2_3 = m * INV_LN2   * W_ih2[3*H1N + jj];
    const float wh2_0 = INV_LN2*W_hh2[0], wh2_1 = INV_LN2*W_hh2[1];
    const float wh2_2 = INV_LN2X2*W_hh2[2], wh2_3 = INV_LN2*W_hh2[3];
    const float b2_0 = INV_LN2*(b_ih2[0] + b_hh2[0]), b2_1 = INV_LN2*(b_ih2[1] + b_hh2[1]);
    const float b2_2 = INV_LN2X2*(b_ih2[2] + b_hh2[2]), b2_3 = INV_LN2*(b_ih2[3] + b_hh2[3]);

    float h1 = jv ? h1s[b*H1N + jj] : 0.0f;
    float c1 = jv ? c1s[b*H1N + jj] : 0.0f;
    const float2 st = h2c2[b];
    float h2 = st.x, c2 = st.y;

    float* __restrict__ orow = out + (long)b * TF;
    float obuf = 0.0f;

    for (int t = T; t < TF; ++t) {
        asm volatile("" : "+v"(wi2_0), "+v"(wi2_1), "+v"(wi2_2), "+v"(wi2_3));
        const float x = h2;

        v2f aI = {fmaf(wx_i, x, b_i), 0.0f};
        v2f aF = {fmaf(wx_f, x, b_f), 0.0f};
        v2f aG = {fmaf(wx_g, x, b_g), 0.0f};
        v2f aO = {fmaf(wx_o, x, b_o), 0.0f};
#pragma unroll
        for (int kk = 0; kk < NP; ++kk) {
            const unsigned int hlo =
                (unsigned int)__builtin_amdgcn_readlane(__float_as_int(h1), 2*kk);
            const unsigned int hhi =
                (unsigned int)__builtin_amdgcn_readlane(__float_as_int(h1), 2*kk + 1);
            const unsigned long long hp =
                ((unsigned long long)hhi << 32) | (unsigned long long)hlo;
            asm("v_pk_fma_f32 %0, %4, %8, %0\n\t"
                "v_pk_fma_f32 %1, %5, %8, %1\n\t"
                "v_pk_fma_f32 %2, %6, %8, %2\n\t"
                "v_pk_fma_f32 %3, %7, %8, %3"
                : "+v"(aI), "+v"(aF), "+v"(aG), "+v"(aO),
                  "+v"(wI[kk]), "+v"(wF[kk]), "+v"(wG[kk]), "+v"(wO[kk])
                : "s"(hp));
        }
        const float gi = sigmoid_s(aI.x + aI.y);
        const float gf = sigmoid_s(aF.x + aF.y);
        const float gg = tanh_s2 (aG.x + aG.y);
        const float go = sigmoid_s(aO.x + aO.y);
        c1 = fmaf(gf, c1, gi * gg);
        h1 = go * tanh_nat(c1);

        float p0 = wi2_0 * h1, p1 = wi2_1 * h1, p2 = wi2_2 * h1, p3 = wi2_3 * h1;
        wave_sum4(p0, p1, p2, p3);
        p0 = rdlane(p0, 63); p1 = rdlane(p1, 63);
        p2 = rdlane(p2, 63); p3 = rdlane(p3, 63);

        const float g2i = sigmoid_s(fmaf(wh2_0, h2, b2_0 + p0));
        const float g2f = sigmoid_s(fmaf(wh2_1, h2, b2_1 + p1));
        const float g2g = tanh_s2 (fmaf(wh2_2, h2, b2_2 + p2));
        const float g2o = sigmoid_s(fmaf(wh2_3, h2, b2_3 + p3));
        c2 = fmaf(g2f, c2, g2i * g2g);
        h2 = g2o * tanh_nat(c2);

        if (j == (t & 63)) obuf = h2;
        if ((t & 63) == 63) orow[t - 63 + j] = obuf;
    }
}

extern "C" void kernel_launch(void* const* d_in, const int* in_sizes, int n_in,
                              void* d_out, int out_size, void* d_ws, size_t ws_size,
                              hipStream_t stream) {
    const float* input = (const float*)d_in[0];
    const float* W_ih1 = (const float*)d_in[1];
    const float* W_hh1 = (const float*)d_in[2];
    const float* b_ih1 = (const float*)d_in[3];
    const float* b_hh1 = (const float*)d_in[4];
    const float* W_ih2 = (const float*)d_in[5];
    const float* W_hh2 = (const float*)d_in[6];
    const float* b_ih2 = (const float*)d_in[7];
    const float* b_hh2 = (const float*)d_in[8];
    float* out = (float*)d_out;

    const int B  = BATCH;
    const int T  = in_sizes[0] / B;      // 1024
    const int TF = out_size   / B;       // 1088

    // ws layout: z-stream [T][B] float4, then h1/c1 states, then h2c2.
    char* ws = (char*)d_ws;
    float4* zws = (float4*)ws;
    size_t off = (size_t)T * B * sizeof(float4);
    float* h1s = (float*)(ws + off);  off += (size_t)B * H1N * sizeof(float);
    float* c1s = (float*)(ws + off);  off += (size_t)B * H1N * sizeof(float);
    float2* h2c2 = (float2*)(ws + off);

    lstm1_pass<<<dim3(B), dim3(WAVE), 0, stream>>>(
        input, W_ih1, W_hh1, b_ih1, b_hh1, W_ih2, zws, h1s, c1s, T);
    lstm2_pass<<<dim3(B / WAVE), dim3(WAVE), 0, stream>>>(
        zws, W_hh2, b_ih2, b_hh2, out, h2c2, T, TF);
    lstm_future<<<dim3(B), dim3(WAVE), 0, stream>>>(
        W_ih1, W_hh1, b_ih1, b_hh1, W_ih2, W_hh2, b_ih2, b_hh2,
        h1s, c1s, h2c2, out, T, TF);
}

// Round 12
// 1290.401 us; speedup vs baseline: 1.1664x; 1.1664x over previous
//
#include <hip/hip_runtime.h>

// R12 = R11's 2-seqs-per-wave fused kernel with the z PIPELINE RE-PHASED
// (R11 failed correctness: z was computed from h1(t-1) but LSTM2 needs
// h1(t)). New schedule, iteration n = 0..TF (one drain iteration):
//   1. matvec over hrow = h1(n-1)  ->  gate pre-sums for LSTM1 step n
//      AND (lanes 51..54) z(n-1) = W_ih2 . h1(n-1)   [z-row trick]
//   2. if n>0: LSTM2 update for step n-1 using z(n-1); emit out[n-1]
//   3. if n<TF: x(n) = input[n] (warm) or h2(n-1) (future, now available);
//      add x-term to pre-sums, activations, c1/h1 update, publish hrow.
// This matches the reference exactly: step t = (LSTM1 with h1(t-1), x(t)) ->
// h1(t); LSTM2 with (h2(t-1), z(t) = W_ih2.h1(t)) -> h2(t). Here step t's
// LSTM2 runs in iteration t+1 off z(t) computed by iteration t+1's matvec.
//
// Carried from R11: 1024 blocks x 1 wave, 2 seqs/wave (weights shared, two
// independent dependency chains hide each other's latency tails); bias folded
// into k=51 slot (hrow[51]=1.0); weights are "+v" operands of the MAC asm
// (proven residency); h1 broadcast via LDS ds_read_b64; no DPP tree, no
// barriers (single wave, in-order LDS pipe gives RAW within the wave).

#define H1N  51
#define NP   26    // k-pairs: k=0..51; k=51 slot = bias (hrow[51]=1.0)
#define WAVE 64

typedef float v2f __attribute__((ext_vector_type(2)));

#define INV_LN2   1.44269504088896340736f
#define INV_LN2X2 2.88539008177792681472f

__device__ __forceinline__ float sigmoid_s(float xs) {   // input pre-scaled by 1/ln2
    return __builtin_amdgcn_rcpf(1.0f + __builtin_amdgcn_exp2f(-xs));
}
__device__ __forceinline__ float tanh_s2(float xs2) {    // input pre-scaled by 2/ln2
    float e = __builtin_amdgcn_exp2f(xs2);
    return fmaf(-2.0f, __builtin_amdgcn_rcpf(e + 1.0f), 1.0f);
}
__device__ __forceinline__ float tanh_nat(float x) {
    return tanh_s2(x * INV_LN2X2);
}
__device__ __forceinline__ float rdlane(float v, int k) {
    return __int_as_float(__builtin_amdgcn_readlane(__float_as_int(v), k));
}

__global__ __attribute__((amdgpu_flat_work_group_size(64, 64),
                          amdgpu_waves_per_eu(1, 1)))
void lstm_seq2(const float* __restrict__ input,   // [B, T]
               const float* __restrict__ W_ih1,   // [204, 1]
               const float* __restrict__ W_hh1,   // [204, 51]
               const float* __restrict__ b_ih1,   // [204]
               const float* __restrict__ b_hh1,   // [204]
               const float* __restrict__ W_ih2,   // [4, 51]
               const float* __restrict__ W_hh2,   // [4, 1]
               const float* __restrict__ b_ih2,   // [4]
               const float* __restrict__ b_hh2,   // [4]
               float* __restrict__ out,           // [B, T+F]
               int T, int TF)
{
    const int j   = threadIdx.x;
    const bool jv = (j < H1N);
    const int jj  = jv ? j : 0;
    const float m = jv ? 1.0f : 0.0f;
    const bool isz = (j >= H1N) && (j < H1N + 4);   // z-row lanes 51..54
    const int  q   = isz ? (j - H1N) : 0;
    const float mz = isz ? 1.0f : 0.0f;
    const float s2q = (q == 2) ? INV_LN2X2 : INV_LN2;  // LSTM2 gate scale

    const int sA = 2 * blockIdx.x, sB = sA + 1;

    const int r_i = jj, r_f = H1N + jj, r_g = 2*H1N + jj, r_o = 3*H1N + jj;
    const float s_i = INV_LN2, s_f = INV_LN2, s_g = INV_LN2X2, s_o = INV_LN2;

    // Weights: lanes<51 = 4 gate rows of unit j (scaled; bias in k=51 slot);
    // lanes 51..54 = W_ih2 row q (scaled) in the gate-i slot.
    v2f wI[NP], wF[NP], wG[NP], wO[NP];
#pragma unroll
    for (int kk = 0; kk < NP; ++kk) {
        const int k0 = 2*kk, k1 = k0 + 1;
        wI[kk].x = m*s_i*W_hh1[r_i*H1N + k0] + mz*s2q*W_ih2[q*H1N + k0];
        wF[kk].x = m*s_f*W_hh1[r_f*H1N + k0];
        wG[kk].x = m*s_g*W_hh1[r_g*H1N + k0];
        wO[kk].x = m*s_o*W_hh1[r_o*H1N + k0];
        if (k1 < H1N) {
            wI[kk].y = m*s_i*W_hh1[r_i*H1N + k1] + mz*s2q*W_ih2[q*H1N + k1];
            wF[kk].y = m*s_f*W_hh1[r_f*H1N + k1];
            wG[kk].y = m*s_g*W_hh1[r_g*H1N + k1];
            wO[kk].y = m*s_o*W_hh1[r_o*H1N + k1];
        } else {   // k1 == 51: bias slot (hrow[51] == 1.0); z-rows get 0
            wI[kk].y = m*s_i*(b_ih1[r_i] + b_hh1[r_i]);
            wF[kk].y = m*s_f*(b_ih1[r_f] + b_hh1[r_f]);
            wG[kk].y = m*s_g*(b_ih1[r_g] + b_hh1[r_g]);
            wO[kk].y = m*s_o*(b_ih1[r_o] + b_hh1[r_o]);
        }
    }
    const float wx_i = m*s_i*W_ih1[r_i];
    const float wx_f = m*s_f*W_ih1[r_f];
    const float wx_g = m*s_g*W_ih1[r_g];
    const float wx_o = m*s_o*W_ih1[r_o];

    // LSTM2 thread-uniform scalars (SGPRs), pre-scaled.
    const float wh2_0 = INV_LN2*W_hh2[0], wh2_1 = INV_LN2*W_hh2[1];
    const float wh2_2 = INV_LN2X2*W_hh2[2], wh2_3 = INV_LN2*W_hh2[3];
    const float b2_0 = INV_LN2*(b_ih2[0] + b_hh2[0]), b2_1 = INV_LN2*(b_ih2[1] + b_hh2[1]);
    const float b2_2 = INV_LN2X2*(b_ih2[2] + b_hh2[2]), b2_3 = INV_LN2*(b_ih2[3] + b_hh2[3]);

    __shared__ __align__(16) float hrowA[WAVE];
    __shared__ __align__(16) float hrowB[WAVE];
    __shared__ __align__(16) float2 zbuf[4];
    hrowA[j] = (j == H1N) ? 1.0f : 0.0f;   // h1(-1)=0; [51]=1.0 (bias lane)
    hrowB[j] = (j == H1N) ? 1.0f : 0.0f;

    float h1A = 0.0f, c1A = 0.0f, h2A = 0.0f, c2A = 0.0f;
    float h1B = 0.0f, c1B = 0.0f, h2B = 0.0f, c2B = 0.0f;

    const float* __restrict__ xrowA = input + (long)sA * T;
    const float* __restrict__ xrowB = input + (long)sB * T;
    float* __restrict__ orowA = out + (long)sA * TF;
    float* __restrict__ orowB = out + (long)sB * TF;

    float xbufA = 0.0f, xbufB = 0.0f, obufA = 0.0f, obufB = 0.0f;

    for (int n = 0; n <= TF; ++n) {
        // ---- 1. matvec over hrow = h1(n-1); weights "+v" asm operands ----
        v2f aIA = {0.0f, 0.0f}, aFA = {0.0f, 0.0f};
        v2f aGA = {0.0f, 0.0f}, aOA = {0.0f, 0.0f};
        v2f aIB = {0.0f, 0.0f}, aFB = {0.0f, 0.0f};
        v2f aGB = {0.0f, 0.0f}, aOB = {0.0f, 0.0f};
#pragma unroll
        for (int kk = 0; kk < NP; ++kk) {
            const v2f hpA = *(const v2f*)&hrowA[2*kk];   // ds_read_b64 bcast
            const v2f hpB = *(const v2f*)&hrowB[2*kk];
            asm("v_pk_fma_f32 %0, %8,  %12, %0\n\t"
                "v_pk_fma_f32 %4, %8,  %13, %4\n\t"
                "v_pk_fma_f32 %1, %9,  %12, %1\n\t"
                "v_pk_fma_f32 %5, %9,  %13, %5\n\t"
                "v_pk_fma_f32 %2, %10, %12, %2\n\t"
                "v_pk_fma_f32 %6, %10, %13, %6\n\t"
                "v_pk_fma_f32 %3, %11, %12, %3\n\t"
                "v_pk_fma_f32 %7, %11, %13, %7"
                : "+v"(aIA), "+v"(aFA), "+v"(aGA), "+v"(aOA),
                  "+v"(aIB), "+v"(aFB), "+v"(aGB), "+v"(aOB),
                  "+v"(wI[kk]), "+v"(wF[kk]), "+v"(wG[kk]), "+v"(wO[kk])
                : "v"(hpA), "v"(hpB));
        }
        // Gate-i pre-sums first: lanes 51..54's are z_q(n-1) -> publish early.
        const float mIA = aIA.x + aIA.y, mIB = aIB.x + aIB.y;
        if (isz) zbuf[q] = make_float2(mIA, mIB);
        const float mFA = aFA.x + aFA.y, mFB = aFB.x + aFB.y;
        const float mGA = aGA.x + aGA.y, mGB = aGB.x + aGB.y;
        const float mOA = aOA.x + aOA.y, mOB = aOB.x + aOB.y;

        // ---- 2. LSTM2 update for step n-1 (uses z(n-1)); emit out[n-1] ----
        if (n > 0) {
            const float2 z0 = zbuf[0], z1 = zbuf[1], z2 = zbuf[2], z3 = zbuf[3];
            {
                const float g2i = sigmoid_s(fmaf(wh2_0, h2A, b2_0 + z0.x));
                const float g2f = sigmoid_s(fmaf(wh2_1, h2A, b2_1 + z1.x));
                const float g2g = tanh_s2 (fmaf(wh2_2, h2A, b2_2 + z2.x));
                const float g2o = sigmoid_s(fmaf(wh2_3, h2A, b2_3 + z3.x));
                c2A = fmaf(g2f, c2A, g2i * g2g);
                h2A = g2o * tanh_nat(c2A);
            }
            {
                const float g2i = sigmoid_s(fmaf(wh2_0, h2B, b2_0 + z0.y));
                const float g2f = sigmoid_s(fmaf(wh2_1, h2B, b2_1 + z1.y));
                const float g2g = tanh_s2 (fmaf(wh2_2, h2B, b2_2 + z2.y));
                const float g2o = sigmoid_s(fmaf(wh2_3, h2B, b2_3 + z3.y));
                c2B = fmaf(g2f, c2B, g2i * g2g);
                h2B = g2o * tanh_nat(c2B);
            }
            const int tt = n - 1;
            if (j == (tt & 63)) { obufA = h2A; obufB = h2B; }
            if ((tt & 63) == 63) {
                orowA[tt - 63 + j] = obufA;
                orowB[tt - 63 + j] = obufB;
            }
        }

        // ---- 3. finish LSTM1 step n: x-term, activations, state update ----
        if (n < TF) {
            float xA, xB;
            if (n < T) {
                if ((n & 63) == 0) { xbufA = xrowA[n + j]; xbufB = xrowB[n + j]; }
                xA = rdlane(xbufA, n & 63);
                xB = rdlane(xbufB, n & 63);
            } else {
                xA = h2A;   // h2(n-1), just computed above
                xB = h2B;
            }
            {
                const float gi = sigmoid_s(fmaf(wx_i, xA, mIA));
                const float gf = sigmoid_s(fmaf(wx_f, xA, mFA));
                const float gg = tanh_s2 (fmaf(wx_g, xA, mGA));
                const float go = sigmoid_s(fmaf(wx_o, xA, mOA));
                c1A = fmaf(gf, c1A, gi * gg);
                h1A = go * tanh_nat(c1A);
            }
            {
                const float gi = sigmoid_s(fmaf(wx_i, xB, mIB));
                const float gf = sigmoid_s(fmaf(wx_f, xB, mFB));
                const float gg = tanh_s2 (fmaf(wx_g, xB, mGB));
                const float go = sigmoid_s(fmaf(wx_o, xB, mOB));
                c1B = fmaf(gf, c1B, gi * gg);
                h1B = go * tanh_nat(c1B);
            }
            if (jv) { hrowA[j] = h1A; hrowB[j] = h1B; }   // publish h1(n)
        }
    }
}

extern "C" void kernel_launch(void* const* d_in, const int* in_sizes, int n_in,
                              void* d_out, int out_size, void* d_ws, size_t ws_size,
                              hipStream_t stream) {
    const float* input = (const float*)d_in[0];
    const float* W_ih1 = (const float*)d_in[1];
    const float* W_hh1 = (const float*)d_in[2];
    const float* b_ih1 = (const float*)d_in[3];
    const float* b_hh1 = (const float*)d_in[4];
    const float* W_ih2 = (const float*)d_in[5];
    const float* W_hh2 = (const float*)d_in[6];
    const float* b_ih2 = (const float*)d_in[7];
    const float* b_hh2 = (const float*)d_in[8];
    float* out = (float*)d_out;

    const int B  = 2048;
    const int T  = in_sizes[0] / B;      // 1024
    const int TF = out_size   / B;       // 1088

    lstm_seq2<<<dim3(B / 2), dim3(WAVE), 0, stream>>>(
        input, W_ih1, W_hh1, b_ih1, b_hh1, W_ih2, W_hh2, b_ih2, b_hh2,
        out, T, TF);
}

// Round 14
// 1274.659 us; speedup vs baseline: 1.1808x; 1.0124x over previous
//
#include <hip/hip_runtime.h>

// R14: same math/pipeline as R12 (proven correct, 2 seqs/wave, z-row trick,
// re-phased LSTM2) but the two sequences are DE-INTERLEAVED into independent
// phases inside one branch-free basic block, so the post-RA scheduler can
// fill one sequence's serial activation tail (trans-op dependency chain,
// ~350 cyc) with the other's 104-pk_fma matvec issue. R12 fused A+B into a
// joint matvec -> joint tail: nothing independent existed during the tail,
// measured as VALUBusy=57% at 1 wave/SIMD.
//
// Facts this builds on (R13 compile error = ground truth):
//  - VOP3P cannot read AGPRs on gfx950 (assembler rejected a[] operands);
//    the RA parks weights in AGPRs and shuttles. Weights are now INPUT-ONLY
//    "v" operands (read-shuttle at worst, no writeback).
//  - v_pk_fma_f32 has NO rate advantage over scalar f32 (157.3 TF spec =
//    scalar full-rate); pk is kept only to halve instruction count.
//  - In-order issue: a wave stalled on a trans chain cannot issue later
//    independent work -> the interleave must be STATIC (scheduler), which
//    requires one straight-line BB: all rare branches hoisted to 64-step
//    boundaries, warm/boundary/future/drain are separate loops.

#define H1N  51
#define NP   26    // k-pairs: k=0..51; k=51 slot = bias (hrow[51]=1.0)
#define WAVE 64

typedef float v2f __attribute__((ext_vector_type(2)));

#define INV_LN2   1.44269504088896340736f
#define INV_LN2X2 2.88539008177792681472f

__device__ __forceinline__ float sigmoid_s(float xs) {   // input pre-scaled by 1/ln2
    return __builtin_amdgcn_rcpf(1.0f + __builtin_amdgcn_exp2f(-xs));
}
__device__ __forceinline__ float tanh_s2(float xs2) {    // input pre-scaled by 2/ln2
    float e = __builtin_amdgcn_exp2f(xs2);
    return fmaf(-2.0f, __builtin_amdgcn_rcpf(e + 1.0f), 1.0f);
}
__device__ __forceinline__ float tanh_nat(float x) {
    return tanh_s2(x * INV_LN2X2);
}
__device__ __forceinline__ float rdlane(float v, int k) {
    return __int_as_float(__builtin_amdgcn_readlane(__float_as_int(v), k));
}

__global__ __attribute__((amdgpu_flat_work_group_size(64, 64),
                          amdgpu_waves_per_eu(1, 1)))
void lstm_seq2(const float* __restrict__ input,   // [B, T]
               const float* __restrict__ W_ih1,   // [204, 1]
               const float* __restrict__ W_hh1,   // [204, 51]
               const float* __restrict__ b_ih1,   // [204]
               const float* __restrict__ b_hh1,   // [204]
               const float* __restrict__ W_ih2,   // [4, 51]
               const float* __restrict__ W_hh2,   // [4, 1]
               const float* __restrict__ b_ih2,   // [4]
               const float* __restrict__ b_hh2,   // [4]
               float* __restrict__ out,           // [B, T+F]
               int T, int TF)
{
    const int j   = threadIdx.x;
    const bool jv = (j < H1N);
    const int jj  = jv ? j : 0;
    const float m = jv ? 1.0f : 0.0f;
    const bool isz = (j >= H1N) && (j < H1N + 4);   // z-row lanes 51..54
    const int  q   = isz ? (j - H1N) : 0;
    const float mz = isz ? 1.0f : 0.0f;
    const float s2q = (q == 2) ? INV_LN2X2 : INV_LN2;  // LSTM2 gate scale

    const int sA = 2 * blockIdx.x, sB = sA + 1;

    const int r_i = jj, r_f = H1N + jj, r_g = 2*H1N + jj, r_o = 3*H1N + jj;
    const float s_i = INV_LN2, s_f = INV_LN2, s_g = INV_LN2X2, s_o = INV_LN2;

    // Weights: lanes<51 = 4 gate rows of unit j (scaled; bias in k=51 slot);
    // lanes 51..54 = W_ih2 row q (scaled) in the gate-i slot.
    v2f wI[NP], wF[NP], wG[NP], wO[NP];
#pragma unroll
    for (int kk = 0; kk < NP; ++kk) {
        const int k0 = 2*kk, k1 = k0 + 1;
        wI[kk].x = m*s_i*W_hh1[r_i*H1N + k0] + mz*s2q*W_ih2[q*H1N + k0];
        wF[kk].x = m*s_f*W_hh1[r_f*H1N + k0];
        wG[kk].x = m*s_g*W_hh1[r_g*H1N + k0];
        wO[kk].x = m*s_o*W_hh1[r_o*H1N + k0];
        if (k1 < H1N) {
            wI[kk].y = m*s_i*W_hh1[r_i*H1N + k1] + mz*s2q*W_ih2[q*H1N + k1];
            wF[kk].y = m*s_f*W_hh1[r_f*H1N + k1];
            wG[kk].y = m*s_g*W_hh1[r_g*H1N + k1];
            wO[kk].y = m*s_o*W_hh1[r_o*H1N + k1];
        } else {   // k1 == 51: bias slot (hrow[51] == 1.0); z-rows get 0
            wI[kk].y = m*s_i*(b_ih1[r_i] + b_hh1[r_i]);
            wF[kk].y = m*s_f*(b_ih1[r_f] + b_hh1[r_f]);
            wG[kk].y = m*s_g*(b_ih1[r_g] + b_hh1[r_g]);
            wO[kk].y = m*s_o*(b_ih1[r_o] + b_hh1[r_o]);
        }
    }
    // One-time pin: anchors the masked-scaled weight values as computed
    // before the loop (blocks remat-from-global), without in-loop round-trips.
#pragma unroll
    for (int kk = 0; kk < NP; ++kk)
        asm volatile("" : "+v"(wI[kk]), "+v"(wF[kk]), "+v"(wG[kk]), "+v"(wO[kk]));

    const float wx_i = m*s_i*W_ih1[r_i];
    const float wx_f = m*s_f*W_ih1[r_f];
    const float wx_g = m*s_g*W_ih1[r_g];
    const float wx_o = m*s_o*W_ih1[r_o];

    // LSTM2 thread-uniform scalars (SGPRs), pre-scaled.
    const float wh2_0 = INV_LN2*W_hh2[0], wh2_1 = INV_LN2*W_hh2[1];
    const float wh2_2 = INV_LN2X2*W_hh2[2], wh2_3 = INV_LN2*W_hh2[3];
    const float b2_0 = INV_LN2*(b_ih2[0] + b_hh2[0]), b2_1 = INV_LN2*(b_ih2[1] + b_hh2[1]);
    const float b2_2 = INV_LN2X2*(b_ih2[2] + b_hh2[2]), b2_3 = INV_LN2*(b_ih2[3] + b_hh2[3]);

    __shared__ __align__(16) float hrowA[WAVE];
    __shared__ __align__(16) float hrowB[WAVE];
    __shared__ __align__(16) float zbA[4];
    __shared__ __align__(16) float zbB[4];
    hrowA[j] = (j == H1N) ? 1.0f : 0.0f;   // h1(-1)=0; [51]=1.0 (bias lane)
    hrowB[j] = (j == H1N) ? 1.0f : 0.0f;

    float c1A = 0.0f, h2A = 0.0f, c2A = 0.0f;
    float c1B = 0.0f, h2B = 0.0f, c2B = 0.0f;

    const float* __restrict__ xrowA = input + (long)sA * T;
    const float* __restrict__ xrowB = input + (long)sB * T;
    float* __restrict__ orowA = out + (long)sA * TF;
    float* __restrict__ orowB = out + (long)sB * TF;

    float xbufA = 0.0f, xbufB = 0.0f, obufA = 0.0f, obufB = 0.0f;

    // One full pipeline phase for one sequence. sel/xmode/do_l2/do_fin are
    // compile-time constants at every call site (constant-folded on inline).
    auto phase = [&](int sel, float& c1, float& h2, float& c2, float& obuf,
                     float xin, int xmode, int do_l2, int do_fin, int tt) {
        float* hrow = sel ? hrowB : hrowA;
        float* zb   = sel ? zbB   : zbA;
        v2f aI = {0.0f, 0.0f}, aF = {0.0f, 0.0f};
        v2f aG = {0.0f, 0.0f}, aO = {0.0f, 0.0f};
#pragma unroll
        for (int kk = 0; kk < NP; ++kk) {
            const v2f hp = *(const v2f*)&hrow[2*kk];   // ds_read_b64 bcast
            asm("v_pk_fma_f32 %0, %4, %8, %0\n\t"
                "v_pk_fma_f32 %1, %5, %8, %1\n\t"
                "v_pk_fma_f32 %2, %6, %8, %2\n\t"
                "v_pk_fma_f32 %3, %7, %8, %3"
                : "+v"(aI), "+v"(aF), "+v"(aG), "+v"(aO)
                : "v"(wI[kk]), "v"(wF[kk]), "v"(wG[kk]), "v"(wO[kk]), "v"(hp));
        }
        const float mI = aI.x + aI.y;
        if (isz) zb[q] = mI;                  // z_q(n-1) from the z-row lanes
        const float mF = aF.x + aF.y, mG = aG.x + aG.y, mO = aO.x + aO.y;

        if (do_l2) {                          // LSTM2 step n-1 (wave-uniform)
            const float4 z = *(const float4*)zb;   // ds_read_b128 bcast
            const float g2i = sigmoid_s(fmaf(wh2_0, h2, b2_0 + z.x));
            const float g2f = sigmoid_s(fmaf(wh2_1, h2, b2_1 + z.y));
            const float g2g = tanh_s2 (fmaf(wh2_2, h2, b2_2 + z.z));
            const float g2o = sigmoid_s(fmaf(wh2_3, h2, b2_3 + z.w));
            c2 = fmaf(g2f, c2, g2i * g2g);
            h2 = g2o * tanh_nat(c2);
            obuf = (j == (tt & 63)) ? h2 : obuf;   // predicated pack
        }
        if (do_fin) {                         // finish LSTM1 step n
            const float x = (xmode == 0) ? xin : h2;
            const float gi = sigmoid_s(fmaf(wx_i, x, mI));
            const float gf = sigmoid_s(fmaf(wx_f, x, mF));
            const float gg = tanh_s2 (fmaf(wx_g, x, mG));
            const float go = sigmoid_s(fmaf(wx_o, x, mO));
            c1 = fmaf(gf, c1, gi * gg);
            const float h1 = go * tanh_nat(c1);
            if (jv) hrow[j] = h1;             // publish h1(n)
        }
    };

    // ---- Prologue: iteration n=0 (no LSTM2 yet) ----
    xbufA = xrowA[j]; xbufB = xrowB[j];
    phase(0, c1A, h2A, c2A, obufA, rdlane(xbufA, 0), 0, 0, 1, 0);
    phase(1, c1B, h2B, c2B, obufB, rdlane(xbufB, 0), 0, 0, 1, 0);

    // ---- Warm loop: n = 1..T-1 (x from input; branch-free hot body) ----
    for (int n = 1; n < T; ++n) {
        if ((n & 63) == 0) { xbufA = xrowA[n + j]; xbufB = xrowB[n + j]; }
        const int u = n & 63;
        const float xA = rdlane(xbufA, u), xB = rdlane(xbufB, u);
        phase(0, c1A, h2A, c2A, obufA, xA, 0, 1, 1, n - 1);
        phase(1, c1B, h2B, c2B, obufB, xB, 0, 1, 1, n - 1);
        if ((n & 63) == 0) {                  // flush for tt = n-64..n-1
            orowA[n - 64 + j] = obufA;
            orowB[n - 64 + j] = obufB;
        }
    }

    // ---- Boundary: n = T (LSTM2 for T-1; first feedback step x=h2) ----
    phase(0, c1A, h2A, c2A, obufA, 0.0f, 1, 1, 1, T - 1);
    phase(1, c1B, h2B, c2B, obufB, 0.0f, 1, 1, 1, T - 1);
    orowA[T - 64 + j] = obufA;                // flush tt = T-64..T-1
    orowB[T - 64 + j] = obufB;

    // ---- Future loop: n = T+1..TF-1 (x = h2 feedback) ----
    for (int n = T + 1; n < TF; ++n) {
        phase(0, c1A, h2A, c2A, obufA, 0.0f, 1, 1, 1, n - 1);
        phase(1, c1B, h2B, c2B, obufB, 0.0f, 1, 1, 1, n - 1);
    }

    // ---- Drain: n = TF (LSTM2 for TF-1 only; no LSTM1 finish) ----
    phase(0, c1A, h2A, c2A, obufA, 0.0f, 1, 1, 0, TF - 1);
    phase(1, c1B, h2B, c2B, obufB, 0.0f, 1, 1, 0, TF - 1);
    orowA[TF - 64 + j] = obufA;               // flush tt = TF-64..TF-1
    orowB[TF - 64 + j] = obufB;
}

extern "C" void kernel_launch(void* const* d_in, const int* in_sizes, int n_in,
                              void* d_out, int out_size, void* d_ws, size_t ws_size,
                              hipStream_t stream) {
    const float* input = (const float*)d_in[0];
    const float* W_ih1 = (const float*)d_in[1];
    const float* W_hh1 = (const float*)d_in[2];
    const float* b_ih1 = (const float*)d_in[3];
    const float* b_hh1 = (const float*)d_in[4];
    const float* W_ih2 = (const float*)d_in[5];
    const float* W_hh2 = (const float*)d_in[6];
    const float* b_ih2 = (const float*)d_in[7];
    const float* b_hh2 = (const float*)d_in[8];
    float* out = (float*)d_out;

    const int B  = 2048;
    const int T  = in_sizes[0] / B;      // 1024
    const int TF = out_size   / B;       // 1088

    lstm_seq2<<<dim3(B / 2), dim3(WAVE), 0, stream>>>(
        input, W_ih1, W_hh1, b_ih1, b_hh1, W_ih2, W_hh2, b_ih2, b_hh2,
        out, T, TF);
}